// Round 2
// baseline (1414.204 us; speedup 1.0000x reference)
//
#include <hip/hip_runtime.h>
#include <hip/hip_bf16.h>

// GCN: h1 = relu(Dinv (A+I) Dinv (x W1) + b1); h2 = relu(same with W2);
// out = mean-pool-by-graph(h2) @ Wl + bl.
// Identity: with hs[u] = (xW)[u]*dinv[u], conv[v] = dinv[v]*(hs[v] + sum_in hs[u]) + b.
// deg[v] = indeg(v)+1 (self loop), shared across both layers -> CSR built once per call.
// ALL float tensors are float32 (reference dtype); ints are int32.

#define HDIM 64

__global__ void k_count(const int* __restrict__ dst, int* __restrict__ cnt, int E) {
    int e = blockIdx.x * 256 + threadIdx.x;
    if (e < E) atomicAdd(&cnt[dst[e]], 1);
}

__global__ void k_alloc(const int* __restrict__ cnt, int* __restrict__ row_start,
                        int* __restrict__ cursor, float* __restrict__ dinv,
                        int* __restrict__ total, int n) {
    int v = blockIdx.x * 256 + threadIdx.x;
    if (v < n) {
        int c = cnt[v];
        int rs = atomicAdd(total, c);   // disjoint ranges; order irrelevant
        row_start[v] = rs;
        cursor[v] = rs;
        dinv[v] = rsqrtf((float)(c + 1));
    }
}

__global__ void k_fill(const int* __restrict__ srcs, const int* __restrict__ dst,
                       int* __restrict__ cursor, int* __restrict__ csr, int E) {
    int e = blockIdx.x * 256 + threadIdx.x;
    if (e < E) {
        int pos = atomicAdd(&cursor[dst[e]], 1);
        csr[pos] = srcs[e];
    }
}

// out[v,f] = dinv[v] * sum_k X[v,k]*W[k,f]   (W float32 row-major [K,64])
template<int K>
__global__ void k_gemm(const float* __restrict__ X, const float* __restrict__ W,
                       const float* __restrict__ dinv, float* __restrict__ out, int n) {
    __shared__ float Ws[K * 64];
    __shared__ float Xs[4][K];
    for (int i = threadIdx.x; i < K * 64; i += 256)
        Ws[i] = W[i];
    __syncthreads();
    int lane = threadIdx.x & 63;
    int wv = threadIdx.x >> 6;
    int v = blockIdx.x * 4 + wv;
    if (v >= n) return;
    const float* xr = X + (size_t)v * K;
    for (int i = lane; i < K; i += 64) Xs[wv][i] = xr[i];
    // no barrier needed: Xs[wv] is private to this wave; wave reads its own writes
    float acc = 0.f;
#pragma unroll
    for (int k = 0; k < K; ++k)
        acc = fmaf(Xs[wv][k], Ws[k * 64 + lane], acc);
    out[(size_t)v * HDIM + lane] = acc * dinv[v];
}

// out[v,f] = relu(dinv[v]*(hs[v,f] + sum_{u in csr[v]} hs[u,f]) + b[f])
__global__ void k_conv(const float* __restrict__ hs, const int* __restrict__ row_start,
                       const int* __restrict__ cnt, const int* __restrict__ csr,
                       const float* __restrict__ dinv, const float* __restrict__ bias,
                       float* __restrict__ out, int n) {
    int wave = (blockIdx.x * 256 + threadIdx.x) >> 6;
    int lane = threadIdx.x & 63;
    if (wave >= n) return;
    int v = wave;
    float acc = hs[(size_t)v * HDIM + lane];
    int rs = row_start[v];
    int c = cnt[v];
    for (int base = 0; base < c; base += 64) {
        int m = c - base; if (m > 64) m = 64;
        int idx = 0;
        if (lane < m) idx = csr[rs + base + lane];
        for (int j = 0; j < m; ++j) {
            int u = __shfl(idx, j, 64);
            acc += hs[(size_t)u * HDIM + lane];
        }
    }
    float r = fmaf(dinv[v], acc, bias[lane]);
    out[(size_t)v * HDIM + lane] = fmaxf(r, 0.f);
}

__global__ void k_pool(const float* __restrict__ h, const int* __restrict__ batch,
                       float* __restrict__ psum, float* __restrict__ pcnt, int n) {
    int t = blockIdx.x * 256 + threadIdx.x;
    int v = t >> 6, lane = t & 63;
    if (v >= n) return;
    int g = batch[v];
    atomicAdd(&psum[g * HDIM + lane], h[(size_t)v * HDIM + lane]);
    if (lane == 0) atomicAdd(&pcnt[g], 1.0f);
}

__global__ void k_final(const float* __restrict__ psum, const float* __restrict__ pcnt,
                        const float* __restrict__ Wl, const float* __restrict__ bl,
                        float* __restrict__ out, int B) {
    int g = blockIdx.x * 256 + threadIdx.x;
    if (g >= B) return;
    float inv = 1.0f / fmaxf(pcnt[g], 1.0f);
    float a0 = bl[0], a1 = bl[1];
    for (int k = 0; k < HDIM; ++k) {
        float p = psum[g * HDIM + k] * inv;
        a0 = fmaf(p, Wl[k * 2 + 0], a0);
        a1 = fmaf(p, Wl[k * 2 + 1], a1);
    }
    out[g * 2 + 0] = a0;
    out[g * 2 + 1] = a1;
}

extern "C" void kernel_launch(void* const* d_in, const int* in_sizes, int n_in,
                              void* d_out, int out_size, void* d_ws, size_t ws_size,
                              hipStream_t stream) {
    const float* x  = (const float*)d_in[0];   // [N,128] f32
    const int* edge = (const int*)d_in[1];     // [2,E] i32
    const int* batch= (const int*)d_in[2];     // [N] i32
    const float* W1 = (const float*)d_in[3];   // [128,64]
    const float* b1 = (const float*)d_in[4];   // [64]
    const float* W2 = (const float*)d_in[5];   // [64,64]
    const float* b2 = (const float*)d_in[6];   // [64]
    const float* Wl = (const float*)d_in[7];   // [64,2]
    const float* bl = (const float*)d_in[8];   // [2]
    float* out = (float*)d_out;

    const int N = in_sizes[2];
    const int E = in_sizes[1] / 2;
    const int B = out_size / 2;
    const int* srcp = edge;
    const int* dstp = edge + E;

    // workspace carve-up (256B aligned); total ~65.8 MB
    char* w = (char*)d_ws;
    auto carve = [&](size_t bytes) { void* p = (void*)w; w += (bytes + 255) & ~(size_t)255; return p; };
    int*   cnt   = (int*)carve((size_t)N * 4);
    int*   rsA   = (int*)carve((size_t)N * 4);
    int*   cur   = (int*)carve((size_t)N * 4);
    float* dinv  = (float*)carve((size_t)N * 4);
    int*   total = (int*)carve(256);
    int*   csr   = (int*)carve((size_t)E * 4);
    float* bufA  = (float*)carve((size_t)N * HDIM * 4);
    float* bufB  = (float*)carve((size_t)N * HDIM * 4);
    float* psum  = (float*)carve((size_t)B * HDIM * 4);
    float* pcnt  = (float*)carve((size_t)B * 4);

    hipMemsetAsync(cnt, 0, (size_t)N * 4, stream);
    hipMemsetAsync(total, 0, 4, stream);
    hipMemsetAsync(psum, 0, (size_t)B * HDIM * 4, stream);
    hipMemsetAsync(pcnt, 0, (size_t)B * 4, stream);

    int ebl = (E + 255) / 256;
    int nbl = (N + 255) / 256;
    int wbl = (N + 3) / 4;   // 4 waves (nodes) per 256-thread block

    k_count<<<ebl, 256, 0, stream>>>(dstp, cnt, E);
    k_alloc<<<nbl, 256, 0, stream>>>(cnt, rsA, cur, dinv, total, N);
    k_fill<<<ebl, 256, 0, stream>>>(srcp, dstp, cur, csr, E);

    k_gemm<128><<<wbl, 256, 0, stream>>>(x, W1, dinv, bufA, N);
    k_conv<<<wbl, 256, 0, stream>>>(bufA, rsA, cnt, csr, dinv, b1, bufB, N);
    k_gemm<64><<<wbl, 256, 0, stream>>>(bufB, W2, dinv, bufA, N);
    k_conv<<<wbl, 256, 0, stream>>>(bufA, rsA, cnt, csr, dinv, b2, bufB, N);

    k_pool<<<wbl, 256, 0, stream>>>(bufB, batch, psum, pcnt, N);
    k_final<<<(B + 255) / 256, 256, 0, stream>>>(psum, pcnt, Wl, bl, out, B);
}

// Round 3
// 1083.363 us; speedup vs baseline: 1.3054x; 1.3054x over previous
//
#include <hip/hip_runtime.h>
#include <hip/hip_bf16.h>

// GCN: h1 = relu(Dinv (A+I) Dinv (x W1) + b1); h2 = relu(same with W2);
// out = mean-pool-by-graph(h2) @ Wl + bl.
// Identity: with hs[u] = (xW)[u]*dinv[u], conv[v] = dinv[v]*(hs[v] + sum_in hs[u]) + b.
// CSR-by-dst built once per call (deg shared across layers).
// R3: pool rebuilt as block-per-graph range-sum (batch is sorted) — the old
// atomicAdd pool was 342us of atomic contention (6.4M RMW on 16K addrs).

#define HDIM 64

__global__ void k_count(const int* __restrict__ dst, int* __restrict__ cnt, int E) {
    int e = blockIdx.x * 256 + threadIdx.x;
    if (e < E) atomicAdd(&cnt[dst[e]], 1);
}

__global__ void k_alloc(const int* __restrict__ cnt, int* __restrict__ row_start,
                        int* __restrict__ cursor, float* __restrict__ dinv,
                        int* __restrict__ total, int n) {
    int v = blockIdx.x * 256 + threadIdx.x;
    if (v < n) {
        int c = cnt[v];
        int rs = atomicAdd(total, c);   // disjoint ranges; order irrelevant
        row_start[v] = rs;
        cursor[v] = rs;
        dinv[v] = rsqrtf((float)(c + 1));
    }
}

__global__ void k_fill(const int* __restrict__ srcs, const int* __restrict__ dst,
                       int* __restrict__ cursor, int* __restrict__ csr, int E) {
    int e = blockIdx.x * 256 + threadIdx.x;
    if (e < E) {
        int pos = atomicAdd(&cursor[dst[e]], 1);
        csr[pos] = srcs[e];
    }
}

// out[v,f] = dinv[v] * sum_k X[v,k]*W[k,f]   (W float32 row-major [K,64])
template<int K>
__global__ void k_gemm(const float* __restrict__ X, const float* __restrict__ W,
                       const float* __restrict__ dinv, float* __restrict__ out, int n) {
    __shared__ float Ws[K * 64];
    __shared__ float Xs[4][K];
    for (int i = threadIdx.x; i < K * 64; i += 256)
        Ws[i] = W[i];
    __syncthreads();
    int lane = threadIdx.x & 63;
    int wv = threadIdx.x >> 6;
    int v = blockIdx.x * 4 + wv;
    if (v >= n) return;
    const float* xr = X + (size_t)v * K;
    for (int i = lane; i < K; i += 64) Xs[wv][i] = xr[i];
    // Xs[wv] is wave-private; wave reads its own writes (no barrier needed)
    float acc = 0.f;
#pragma unroll
    for (int k = 0; k < K; ++k)
        acc = fmaf(Xs[wv][k], Ws[k * 64 + lane], acc);
    out[(size_t)v * HDIM + lane] = acc * dinv[v];
}

// out[v,f] = relu(dinv[v]*(hs[v,f] + sum_{u in csr[v]} hs[u,f]) + b[f])
__global__ void k_conv(const float* __restrict__ hs, const int* __restrict__ row_start,
                       const int* __restrict__ cnt, const int* __restrict__ csr,
                       const float* __restrict__ dinv, const float* __restrict__ bias,
                       float* __restrict__ out, int n) {
    int wave = (blockIdx.x * 256 + threadIdx.x) >> 6;
    int lane = threadIdx.x & 63;
    if (wave >= n) return;
    int v = wave;
    float acc = hs[(size_t)v * HDIM + lane];
    int rs = row_start[v];
    int c = cnt[v];
    for (int base = 0; base < c; base += 64) {
        int m = c - base; if (m > 64) m = 64;
        int idx = 0;
        if (lane < m) idx = csr[rs + base + lane];
        for (int j = 0; j < m; ++j) {
            int u = __shfl(idx, j, 64);
            acc += hs[(size_t)u * HDIM + lane];
        }
    }
    float r = fmaf(dinv[v], acc, bias[lane]);
    out[(size_t)v * HDIM + lane] = fmaxf(r, 0.f);
}

static __device__ __forceinline__ int lower_bound(const int* __restrict__ a, int n, int key) {
    int lo = 0, hi = n;
    while (lo < hi) {
        int mid = (lo + hi) >> 1;
        if (a[mid] < key) lo = mid + 1; else hi = mid;
    }
    return lo;
}

// One block per graph g: mean over batch-range [lo,hi), then @ Wl + bl.
// batch is sorted, so the range is contiguous; zero atomics.
__global__ void k_pool_final(const float* __restrict__ h, const int* __restrict__ batch,
                             const float* __restrict__ Wl, const float* __restrict__ bl,
                             float* __restrict__ out, int N) {
    int g = blockIdx.x;
    int lo = lower_bound(batch, N, g);
    int hi = lower_bound(batch, N, g + 1);
    int lane = threadIdx.x & 63;
    int wv = threadIdx.x >> 6;
    float acc = 0.f;
    for (int v = lo + wv; v < hi; v += 4)
        acc += h[(size_t)v * HDIM + lane];
    __shared__ float red[4][HDIM];
    red[wv][lane] = acc;
    __syncthreads();
    if (wv == 0) {
        float s = red[0][lane] + red[1][lane] + red[2][lane] + red[3][lane];
        float p = s / fmaxf((float)(hi - lo), 1.0f);
        float c0 = p * Wl[lane * 2 + 0];
        float c1 = p * Wl[lane * 2 + 1];
        #pragma unroll
        for (int off = 32; off; off >>= 1) {
            c0 += __shfl_down(c0, off, 64);
            c1 += __shfl_down(c1, off, 64);
        }
        if (lane == 0) {
            out[g * 2 + 0] = c0 + bl[0];
            out[g * 2 + 1] = c1 + bl[1];
        }
    }
}

extern "C" void kernel_launch(void* const* d_in, const int* in_sizes, int n_in,
                              void* d_out, int out_size, void* d_ws, size_t ws_size,
                              hipStream_t stream) {
    const float* x  = (const float*)d_in[0];   // [N,128] f32
    const int* edge = (const int*)d_in[1];     // [2,E] i32
    const int* batch= (const int*)d_in[2];     // [N] i32 (sorted)
    const float* W1 = (const float*)d_in[3];   // [128,64]
    const float* b1 = (const float*)d_in[4];   // [64]
    const float* W2 = (const float*)d_in[5];   // [64,64]
    const float* b2 = (const float*)d_in[6];   // [64]
    const float* Wl = (const float*)d_in[7];   // [64,2]
    const float* bl = (const float*)d_in[8];   // [2]
    float* out = (float*)d_out;

    const int N = in_sizes[2];
    const int E = in_sizes[1] / 2;
    const int B = out_size / 2;
    const int* srcp = edge;
    const int* dstp = edge + E;

    // workspace carve-up (256B aligned)
    char* w = (char*)d_ws;
    auto carve = [&](size_t bytes) { void* p = (void*)w; w += (bytes + 255) & ~(size_t)255; return p; };
    int*   cnt   = (int*)carve((size_t)N * 4);
    int*   rsA   = (int*)carve((size_t)N * 4);
    int*   cur   = (int*)carve((size_t)N * 4);
    float* dinv  = (float*)carve((size_t)N * 4);
    int*   total = (int*)carve(256);
    int*   csr   = (int*)carve((size_t)E * 4);
    float* bufA  = (float*)carve((size_t)N * HDIM * 4);
    float* bufB  = (float*)carve((size_t)N * HDIM * 4);

    hipMemsetAsync(cnt, 0, (size_t)N * 4, stream);
    hipMemsetAsync(total, 0, 4, stream);

    int ebl = (E + 255) / 256;
    int nbl = (N + 255) / 256;
    int wbl = (N + 3) / 4;   // 4 waves (nodes) per 256-thread block

    k_count<<<ebl, 256, 0, stream>>>(dstp, cnt, E);
    k_alloc<<<nbl, 256, 0, stream>>>(cnt, rsA, cur, dinv, total, N);
    k_fill<<<ebl, 256, 0, stream>>>(srcp, dstp, cur, csr, E);

    k_gemm<128><<<wbl, 256, 0, stream>>>(x, W1, dinv, bufA, N);
    k_conv<<<wbl, 256, 0, stream>>>(bufA, rsA, cnt, csr, dinv, b1, bufB, N);
    k_gemm<64><<<wbl, 256, 0, stream>>>(bufB, W2, dinv, bufA, N);
    k_conv<<<wbl, 256, 0, stream>>>(bufA, rsA, cnt, csr, dinv, b2, bufB, N);

    k_pool_final<<<B, 256, 0, stream>>>(bufB, batch, Wl, bl, out, N);
}

// Round 4
// 715.060 us; speedup vs baseline: 1.9777x; 1.5151x over previous
//
#include <hip/hip_runtime.h>
#include <hip/hip_bf16.h>

// GCN: h1 = relu(Dinv (A+I) Dinv (x W1) + b1); h2 = relu(same with W2);
// out = mean-pool-by-graph(h2) @ Wl + bl.
// Identity: with hs[u] = (xW)[u]*dinv[u], conv[v] = dinv[v]*(hs[v] + sum_in hs[u]) + b.
// R4: CSR build rebuilt as 256-way counting sort. Old k_fill scattered 3.2M
// single-dword stores randomly over 12.8MB -> 194MB HBM write traffic (16x
// amplification, partial lines from 8 non-coherent XCD L2s) + 3.2M contended
// atomic RMWs = 305us. Now: bucket-by-dst (coalesced run writes), then one
// WG per bucket fills a 50KB L2-local csr window with LDS cursors.

#define HDIM 64
#define NB 256     // dst-range buckets

__global__ void k_bcount(const int* __restrict__ dst, int* __restrict__ bucket_cnt,
                         int E, int npb, int chunk) {
    __shared__ int lh[NB];
    int tid = threadIdx.x;
    if (tid < NB) lh[tid] = 0;
    __syncthreads();
    int e0 = blockIdx.x * chunk, e1 = min(E, e0 + chunk);
    for (int e = e0 + tid; e < e1; e += 1024)
        atomicAdd(&lh[(unsigned)dst[e] / (unsigned)npb], 1);
    __syncthreads();
    if (tid < NB && lh[tid]) atomicAdd(&bucket_cnt[tid], lh[tid]);
}

__global__ void k_bscan(const int* __restrict__ bucket_cnt, int* __restrict__ bucket_start,
                        int* __restrict__ bucket_cursor) {
    if (threadIdx.x == 0) {
        int s = 0;
        for (int i = 0; i < NB; ++i) { bucket_start[i] = s; bucket_cursor[i] = s; s += bucket_cnt[i]; }
        bucket_start[NB] = s;
    }
}

__global__ __launch_bounds__(1024) void k_bscatter(const int* __restrict__ src,
        const int* __restrict__ dst, int* __restrict__ bucket_cursor,
        int2* __restrict__ ebuf, int E, int npb, int chunk) {
    __shared__ int lh[NB], base[NB], lcur[NB];
    int tid = threadIdx.x;
    if (tid < NB) lh[tid] = 0;
    __syncthreads();
    int e0 = blockIdx.x * chunk, e1 = min(E, e0 + chunk);
    for (int e = e0 + tid; e < e1; e += 1024)
        atomicAdd(&lh[(unsigned)dst[e] / (unsigned)npb], 1);
    __syncthreads();
    if (tid < NB) {
        base[tid] = lh[tid] ? atomicAdd(&bucket_cursor[tid], lh[tid]) : 0;
        lcur[tid] = 0;
    }
    __syncthreads();
    for (int e = e0 + tid; e < e1; e += 1024) {
        int d = dst[e];
        int b = (unsigned)d / (unsigned)npb;
        int off = atomicAdd(&lcur[b], 1);
        ebuf[base[b] + off] = make_int2(src[e], d);   // contiguous runs per (block,bucket)
    }
}

// One WG per bucket: LDS histogram -> LDS scan -> row_start/cnt/dinv + csr fill.
// All csr stores for the bucket come from one CU -> full lines, L2-local.
__global__ __launch_bounds__(1024) void k_bfill(const int2* __restrict__ ebuf,
        const int* __restrict__ bucket_start, int* __restrict__ row_start,
        int* __restrict__ cnt, float* __restrict__ dinv, int* __restrict__ csr,
        int N, int npb) {
    __shared__ int h[512], p[512], c[512];
    int b = blockIdx.x, tid = threadIdx.x;
    int vlo = b * npb;
    int vcnt = min(npb, N - vlo);
    if (vcnt <= 0) return;                    // uniform across block
    for (int i = tid; i < 512; i += 1024) h[i] = 0;
    __syncthreads();
    int e0 = bucket_start[b], e1 = bucket_start[b + 1];
    for (int e = e0 + tid; e < e1; e += 1024)
        atomicAdd(&h[ebuf[e].y - vlo], 1);
    __syncthreads();
    if (tid < 512) p[tid] = h[tid];
    __syncthreads();
    for (int off = 1; off < 512; off <<= 1) { // Hillis-Steele inclusive scan
        int v = 0;
        if (tid < 512 && tid >= off) v = p[tid - off];
        __syncthreads();
        if (tid < 512) p[tid] += v;
        __syncthreads();
    }
    if (tid < vcnt) {
        int excl = p[tid] - h[tid];
        int v = vlo + tid;
        row_start[v] = e0 + excl;
        cnt[v] = h[tid];
        dinv[v] = rsqrtf((float)(h[tid] + 1));
        c[tid] = excl;
    }
    __syncthreads();
    for (int e = e0 + tid; e < e1; e += 1024) {
        int2 ed = ebuf[e];
        int off = atomicAdd(&c[ed.y - vlo], 1);
        csr[e0 + off] = ed.x;
    }
}

// out[v,f] = dinv[v] * sum_k X[v,k]*W[k,f]   (W float32 row-major [K,64])
template<int K>
__global__ void k_gemm(const float* __restrict__ X, const float* __restrict__ W,
                       const float* __restrict__ dinv, float* __restrict__ out, int n) {
    __shared__ float Ws[K * 64];
    __shared__ float Xs[4][K];
    for (int i = threadIdx.x; i < K * 64; i += 256)
        Ws[i] = W[i];
    __syncthreads();
    int lane = threadIdx.x & 63;
    int wv = threadIdx.x >> 6;
    int v = blockIdx.x * 4 + wv;
    if (v >= n) return;
    const float* xr = X + (size_t)v * K;
    for (int i = lane; i < K; i += 64) Xs[wv][i] = xr[i];
    // Xs[wv] is wave-private; wave reads its own writes (no barrier needed)
    float acc = 0.f;
#pragma unroll
    for (int k = 0; k < K; ++k)
        acc = fmaf(Xs[wv][k], Ws[k * 64 + lane], acc);
    out[(size_t)v * HDIM + lane] = acc * dinv[v];
}

// out[v,f] = relu(dinv[v]*(hs[v,f] + sum_{u in csr[v]} hs[u,f]) + b[f])
__global__ void k_conv(const float* __restrict__ hs, const int* __restrict__ row_start,
                       const int* __restrict__ cnt, const int* __restrict__ csr,
                       const float* __restrict__ dinv, const float* __restrict__ bias,
                       float* __restrict__ out, int n) {
    int wave = (blockIdx.x * 256 + threadIdx.x) >> 6;
    int lane = threadIdx.x & 63;
    if (wave >= n) return;
    int v = wave;
    float acc = hs[(size_t)v * HDIM + lane];
    int rs = row_start[v];
    int c = cnt[v];
    for (int base = 0; base < c; base += 64) {
        int m = c - base; if (m > 64) m = 64;
        int idx = 0;
        if (lane < m) idx = csr[rs + base + lane];
        for (int j = 0; j < m; ++j) {
            int u = __shfl(idx, j, 64);
            acc += hs[(size_t)u * HDIM + lane];
        }
    }
    float r = fmaf(dinv[v], acc, bias[lane]);
    out[(size_t)v * HDIM + lane] = fmaxf(r, 0.f);
}

static __device__ __forceinline__ int lower_bound(const int* __restrict__ a, int n, int key) {
    int lo = 0, hi = n;
    while (lo < hi) {
        int mid = (lo + hi) >> 1;
        if (a[mid] < key) lo = mid + 1; else hi = mid;
    }
    return lo;
}

// One block per graph g: mean over batch-range [lo,hi) (batch sorted), @ Wl + bl.
__global__ void k_pool_final(const float* __restrict__ h, const int* __restrict__ batch,
                             const float* __restrict__ Wl, const float* __restrict__ bl,
                             float* __restrict__ out, int N) {
    int g = blockIdx.x;
    int lo = lower_bound(batch, N, g);
    int hi = lower_bound(batch, N, g + 1);
    int lane = threadIdx.x & 63;
    int wv = threadIdx.x >> 6;
    float acc = 0.f;
    for (int v = lo + wv; v < hi; v += 4)
        acc += h[(size_t)v * HDIM + lane];
    __shared__ float red[4][HDIM];
    red[wv][lane] = acc;
    __syncthreads();
    if (wv == 0) {
        float s = red[0][lane] + red[1][lane] + red[2][lane] + red[3][lane];
        float p = s / fmaxf((float)(hi - lo), 1.0f);
        float c0 = p * Wl[lane * 2 + 0];
        float c1 = p * Wl[lane * 2 + 1];
        #pragma unroll
        for (int off = 32; off; off >>= 1) {
            c0 += __shfl_down(c0, off, 64);
            c1 += __shfl_down(c1, off, 64);
        }
        if (lane == 0) {
            out[g * 2 + 0] = c0 + bl[0];
            out[g * 2 + 1] = c1 + bl[1];
        }
    }
}

extern "C" void kernel_launch(void* const* d_in, const int* in_sizes, int n_in,
                              void* d_out, int out_size, void* d_ws, size_t ws_size,
                              hipStream_t stream) {
    const float* x  = (const float*)d_in[0];   // [N,128] f32
    const int* edge = (const int*)d_in[1];     // [2,E] i32
    const int* batch= (const int*)d_in[2];     // [N] i32 (sorted)
    const float* W1 = (const float*)d_in[3];   // [128,64]
    const float* b1 = (const float*)d_in[4];   // [64]
    const float* W2 = (const float*)d_in[5];   // [64,64]
    const float* b2 = (const float*)d_in[6];   // [64]
    const float* Wl = (const float*)d_in[7];   // [64,2]
    const float* bl = (const float*)d_in[8];   // [2]
    float* out = (float*)d_out;

    const int N = in_sizes[2];
    const int E = in_sizes[1] / 2;
    const int B = out_size / 2;
    const int* srcp = edge;
    const int* dstp = edge + E;
    const int npb = (N + NB - 1) / NB;         // nodes per bucket (391 @ N=100K, <=512)

    // workspace carve-up (256B aligned)
    char* w = (char*)d_ws;
    auto carve = [&](size_t bytes) { void* p = (void*)w; w += (bytes + 255) & ~(size_t)255; return p; };
    int*   cnt    = (int*)carve((size_t)N * 4);
    int*   rsA    = (int*)carve((size_t)N * 4);
    float* dinv   = (float*)carve((size_t)N * 4);
    int*   bcnt   = (int*)carve((NB + 8) * 4);
    int*   bstart = (int*)carve((NB + 8) * 4);
    int*   bcur   = (int*)carve((NB + 8) * 4);
    int*   csr    = (int*)carve((size_t)E * 4);
    float* bufA   = (float*)carve((size_t)N * HDIM * 4);
    float* bufB   = (float*)carve((size_t)N * HDIM * 4);
    int2*  ebuf   = (int2*)bufA;   // E*8 == N*HDIM*4 bytes; consumed by k_bfill before gemm1 writes bufA

    hipMemsetAsync(bcnt, 0, NB * 4, stream);

    const int SGRID = 256;                      // blocks for count/scatter
    const int chunk = (E + SGRID - 1) / SGRID;  // edges per block
    int wbl = (N + 3) / 4;                      // 4 waves (nodes) per 256-thread block

    k_bcount<<<SGRID, 1024, 0, stream>>>(dstp, bcnt, E, npb, chunk);
    k_bscan<<<1, 64, 0, stream>>>(bcnt, bstart, bcur);
    k_bscatter<<<SGRID, 1024, 0, stream>>>(srcp, dstp, bcur, ebuf, E, npb, chunk);
    k_bfill<<<NB, 1024, 0, stream>>>(ebuf, bstart, rsA, cnt, dinv, csr, N, npb);

    k_gemm<128><<<wbl, 256, 0, stream>>>(x, W1, dinv, bufA, N);
    k_conv<<<wbl, 256, 0, stream>>>(bufA, rsA, cnt, csr, dinv, b1, bufB, N);
    k_gemm<64><<<wbl, 256, 0, stream>>>(bufB, W2, dinv, bufA, N);
    k_conv<<<wbl, 256, 0, stream>>>(bufA, rsA, cnt, csr, dinv, b2, bufB, N);

    k_pool_final<<<B, 256, 0, stream>>>(bufB, batch, Wl, bl, out, N);
}

// Round 5
// 584.103 us; speedup vs baseline: 2.4212x; 1.2242x over previous
//
#include <hip/hip_runtime.h>
#include <hip/hip_bf16.h>

// GCN: h1 = relu(Dinv (A+I) Dinv (x W1) + b1); h2 = relu(same with W2);
// out = mean-pool-by-graph(h2) @ Wl + bl.
// Identity: with hs[u] = (xW)[u]*dinv[u], conv[v] = dinv[v]*(hs[v] + sum_in hs[u]) + b.
// R5: gather operand hs stored as packed bf16 (128B/row, was 256B fp32):
// conv FETCH was 363MB @ 56% L2 miss (25.6MB footprint >> 4MB XCD L2).
// Accumulation/bias/relu stay fp32. ebuf packed to 1 uint/edge ((ld<<17)|src).

#define HDIM 64
#define NB 256     // dst-range buckets (requires N <= 131072: src fits 17 bits, local dst fits 9)

static __device__ __forceinline__ unsigned bf16_bits(float f) {  // RNE
    unsigned u = __float_as_uint(f);
    return (u + 0x7fff + ((u >> 16) & 1)) >> 16;
}

__global__ void k_bcount(const int* __restrict__ dst, int* __restrict__ bucket_cnt,
                         int E, int npb, int chunk) {
    __shared__ int lh[NB];
    int tid = threadIdx.x;
    if (tid < NB) lh[tid] = 0;
    __syncthreads();
    int e0 = blockIdx.x * chunk, e1 = min(E, e0 + chunk);
    for (int e = e0 + tid; e < e1; e += 1024)
        atomicAdd(&lh[(unsigned)dst[e] / (unsigned)npb], 1);
    __syncthreads();
    if (tid < NB && lh[tid]) atomicAdd(&bucket_cnt[tid], lh[tid]);
}

__global__ void k_bscan(const int* __restrict__ bucket_cnt, int* __restrict__ bucket_start,
                        int* __restrict__ bucket_cursor) {
    if (threadIdx.x == 0) {
        int s = 0;
        for (int i = 0; i < NB; ++i) { bucket_start[i] = s; bucket_cursor[i] = s; s += bucket_cnt[i]; }
        bucket_start[NB] = s;
    }
}

__global__ __launch_bounds__(1024) void k_bscatter(const int* __restrict__ src,
        const int* __restrict__ dst, int* __restrict__ bucket_cursor,
        unsigned* __restrict__ ebuf, int E, int npb, int chunk) {
    __shared__ int lh[NB], base[NB], lcur[NB];
    int tid = threadIdx.x;
    if (tid < NB) lh[tid] = 0;
    __syncthreads();
    int e0 = blockIdx.x * chunk, e1 = min(E, e0 + chunk);
    for (int e = e0 + tid; e < e1; e += 1024)
        atomicAdd(&lh[(unsigned)dst[e] / (unsigned)npb], 1);
    __syncthreads();
    if (tid < NB) {
        base[tid] = lh[tid] ? atomicAdd(&bucket_cursor[tid], lh[tid]) : 0;
        lcur[tid] = 0;
    }
    __syncthreads();
    for (int e = e0 + tid; e < e1; e += 1024) {
        int d = dst[e];
        unsigned b = (unsigned)d / (unsigned)npb;
        unsigned ld = (unsigned)d - b * (unsigned)npb;
        int off = atomicAdd(&lcur[b], 1);
        ebuf[base[b] + off] = (ld << 17) | (unsigned)src[e];  // contiguous runs
    }
}

// One WG per bucket: LDS histogram -> scan -> row_start/cnt/dinv + csr fill.
__global__ __launch_bounds__(1024) void k_bfill(const unsigned* __restrict__ ebuf,
        const int* __restrict__ bucket_start, int* __restrict__ row_start,
        int* __restrict__ cnt, float* __restrict__ dinv, int* __restrict__ csr,
        int N, int npb) {
    __shared__ int h[512], p[512], c[512];
    int b = blockIdx.x, tid = threadIdx.x;
    int vlo = b * npb;
    int vcnt = min(npb, N - vlo);
    if (vcnt <= 0) return;                    // uniform across block
    for (int i = tid; i < 512; i += 1024) h[i] = 0;
    __syncthreads();
    int e0 = bucket_start[b], e1 = bucket_start[b + 1];
    for (int e = e0 + tid; e < e1; e += 1024)
        atomicAdd(&h[ebuf[e] >> 17], 1);
    __syncthreads();
    if (tid < 512) p[tid] = h[tid];
    __syncthreads();
    for (int off = 1; off < 512; off <<= 1) { // Hillis-Steele inclusive scan
        int v = 0;
        if (tid < 512 && tid >= off) v = p[tid - off];
        __syncthreads();
        if (tid < 512) p[tid] += v;
        __syncthreads();
    }
    if (tid < vcnt) {
        int excl = p[tid] - h[tid];
        int v = vlo + tid;
        row_start[v] = e0 + excl;
        cnt[v] = h[tid];
        dinv[v] = rsqrtf((float)(h[tid] + 1));
        c[tid] = excl;
    }
    __syncthreads();
    for (int e = e0 + tid; e < e1; e += 1024) {
        unsigned ed = ebuf[e];
        int off = atomicAdd(&c[ed >> 17], 1);
        csr[e0 + off] = (int)(ed & 0x1FFFFu);
    }
}

// hsb[v] = bf16x2-packed row of dinv[v] * (X[v] @ W)   (W f32 row-major [K,64])
template<int K>
__global__ void k_gemm(const float* __restrict__ X, const float* __restrict__ W,
                       const float* __restrict__ dinv, unsigned* __restrict__ hsb, int n) {
    __shared__ float Ws[K * 64];
    __shared__ float Xs[4][K];
    for (int i = threadIdx.x; i < K * 64; i += 256)
        Ws[i] = W[i];
    __syncthreads();
    int lane = threadIdx.x & 63;
    int wv = threadIdx.x >> 6;
    int v = blockIdx.x * 4 + wv;
    if (v >= n) return;
    const float* xr = X + (size_t)v * K;
    for (int i = lane; i < K; i += 64) Xs[wv][i] = xr[i];
    // Xs[wv] is wave-private; wave reads its own writes (no barrier needed)
    float acc = 0.f;
#pragma unroll
    for (int k = 0; k < K; ++k)
        acc = fmaf(Xs[wv][k], Ws[k * 64 + lane], acc);
    float val = acc * dinv[v];
    float other = __shfl_xor(val, 1, 64);      // partner feature
    if ((lane & 1) == 0)
        hsb[(size_t)v * 32 + (lane >> 1)] = bf16_bits(val) | (bf16_bits(other) << 16);
}

// out[v,f] = relu(dinv[v]*(hs[v,f] + sum_{u in csr[v]} hs[u,f]) + b[f])
// hs rows are 32 uints (bf16x2). Half-wave per neighbor row: 2 neighbors/step.
__global__ void k_conv(const unsigned* __restrict__ hsb, const int* __restrict__ row_start,
                       const int* __restrict__ cnt, const int* __restrict__ csr,
                       const float* __restrict__ dinv, const float* __restrict__ bias,
                       float* __restrict__ out, int n) {
    int wave = (blockIdx.x * 256 + threadIdx.x) >> 6;
    int lane = threadIdx.x & 63;
    if (wave >= n) return;
    int v = wave;
    int half = lane >> 5, sub = lane & 31;
    float ax = 0.f, ay = 0.f;
    if (half == 0) {                           // self-loop term
        unsigned s = hsb[(size_t)v * 32 + sub];
        ax = __uint_as_float(s << 16);
        ay = __uint_as_float(s & 0xffff0000u);
    }
    int rs = row_start[v];
    int c = cnt[v];
    for (int base = 0; base < c; base += 64) {
        int m = c - base; if (m > 64) m = 64;
        int idx = 0;
        if (lane < m) idx = csr[rs + base + lane];
        for (int j = 0; j < m; j += 2) {
            int u = __shfl(idx, j + half, 64);
            if (j + half < m) {
                unsigned wn = hsb[(size_t)u * 32 + sub];
                ax += __uint_as_float(wn << 16);
                ay += __uint_as_float(wn & 0xffff0000u);
            }
        }
    }
    ax += __shfl_xor(ax, 32, 64);
    ay += __shfl_xor(ay, 32, 64);
    if (half == 0) {
        float dv = dinv[v];
        float2 bb = ((const float2*)bias)[sub];
        float r0 = fmaxf(fmaf(dv, ax, bb.x), 0.f);
        float r1 = fmaxf(fmaf(dv, ay, bb.y), 0.f);
        ((float2*)out)[(size_t)v * 32 + sub] = make_float2(r0, r1);
    }
}

static __device__ __forceinline__ int lower_bound(const int* __restrict__ a, int n, int key) {
    int lo = 0, hi = n;
    while (lo < hi) {
        int mid = (lo + hi) >> 1;
        if (a[mid] < key) lo = mid + 1; else hi = mid;
    }
    return lo;
}

// One block per graph g: mean over batch-range [lo,hi) (batch sorted), @ Wl + bl.
__global__ void k_pool_final(const float* __restrict__ h, const int* __restrict__ batch,
                             const float* __restrict__ Wl, const float* __restrict__ bl,
                             float* __restrict__ out, int N) {
    int g = blockIdx.x;
    int lo = lower_bound(batch, N, g);
    int hi = lower_bound(batch, N, g + 1);
    int lane = threadIdx.x & 63;
    int wv = threadIdx.x >> 6;
    float acc = 0.f;
    for (int v = lo + wv; v < hi; v += 4)
        acc += h[(size_t)v * HDIM + lane];
    __shared__ float red[4][HDIM];
    red[wv][lane] = acc;
    __syncthreads();
    if (wv == 0) {
        float s = red[0][lane] + red[1][lane] + red[2][lane] + red[3][lane];
        float p = s / fmaxf((float)(hi - lo), 1.0f);
        float c0 = p * Wl[lane * 2 + 0];
        float c1 = p * Wl[lane * 2 + 1];
        #pragma unroll
        for (int off = 32; off; off >>= 1) {
            c0 += __shfl_down(c0, off, 64);
            c1 += __shfl_down(c1, off, 64);
        }
        if (lane == 0) {
            out[g * 2 + 0] = c0 + bl[0];
            out[g * 2 + 1] = c1 + bl[1];
        }
    }
}

extern "C" void kernel_launch(void* const* d_in, const int* in_sizes, int n_in,
                              void* d_out, int out_size, void* d_ws, size_t ws_size,
                              hipStream_t stream) {
    const float* x  = (const float*)d_in[0];   // [N,128] f32
    const int* edge = (const int*)d_in[1];     // [2,E] i32
    const int* batch= (const int*)d_in[2];     // [N] i32 (sorted)
    const float* W1 = (const float*)d_in[3];   // [128,64]
    const float* b1 = (const float*)d_in[4];   // [64]
    const float* W2 = (const float*)d_in[5];   // [64,64]
    const float* b2 = (const float*)d_in[6];   // [64]
    const float* Wl = (const float*)d_in[7];   // [64,2]
    const float* bl = (const float*)d_in[8];   // [2]
    float* out = (float*)d_out;

    const int N = in_sizes[2];
    const int E = in_sizes[1] / 2;
    const int B = out_size / 2;
    const int* srcp = edge;
    const int* dstp = edge + E;
    const int npb = (N + NB - 1) / NB;         // nodes per bucket (391 @ N=100K, <=512)

    // workspace carve-up (256B aligned); ~52 MB
    char* w = (char*)d_ws;
    auto carve = [&](size_t bytes) { void* p = (void*)w; w += (bytes + 255) & ~(size_t)255; return p; };
    int*      cnt    = (int*)carve((size_t)N * 4);
    int*      rsA    = (int*)carve((size_t)N * 4);
    float*    dinv   = (float*)carve((size_t)N * 4);
    int*      bcnt   = (int*)carve((NB + 8) * 4);
    int*      bstart = (int*)carve((NB + 8) * 4);
    int*      bcur   = (int*)carve((NB + 8) * 4);
    int*      csr    = (int*)carve((size_t)E * 4);
    unsigned* ebuf   = (unsigned*)carve((size_t)E * 4);
    unsigned* hsb    = (unsigned*)carve((size_t)N * 32 * 4);   // bf16x2-packed hs
    float*    bufB   = (float*)carve((size_t)N * HDIM * 4);    // fp32 conv output

    hipMemsetAsync(bcnt, 0, NB * 4, stream);

    const int SGRID = 256;                      // blocks for count/scatter
    const int chunk = (E + SGRID - 1) / SGRID;  // edges per block
    int wbl = (N + 3) / 4;                      // 4 waves (nodes) per 256-thread block

    k_bcount<<<SGRID, 1024, 0, stream>>>(dstp, bcnt, E, npb, chunk);
    k_bscan<<<1, 64, 0, stream>>>(bcnt, bstart, bcur);
    k_bscatter<<<SGRID, 1024, 0, stream>>>(srcp, dstp, bcur, ebuf, E, npb, chunk);
    k_bfill<<<NB, 1024, 0, stream>>>(ebuf, bstart, rsA, cnt, dinv, csr, N, npb);

    k_gemm<128><<<wbl, 256, 0, stream>>>(x, W1, dinv, hsb, N);
    k_conv<<<wbl, 256, 0, stream>>>(hsb, rsA, cnt, csr, dinv, b1, bufB, N);
    k_gemm<64><<<wbl, 256, 0, stream>>>(bufB, W2, dinv, hsb, N);
    k_conv<<<wbl, 256, 0, stream>>>(hsb, rsA, cnt, csr, dinv, b2, bufB, N);

    k_pool_final<<<B, 256, 0, stream>>>(bufB, batch, Wl, bl, out, N);
}

// Round 6
// 494.450 us; speedup vs baseline: 2.8602x; 1.1813x over previous
//
#include <hip/hip_runtime.h>
#include <hip/hip_bf16.h>

// GCN: h1 = relu(Dinv (A+I) Dinv (x W1) + b1); h2 = relu(same with W2);
// out = mean-pool-by-graph(h2) @ Wl + bl.
// Identity: hs[u] = (xW)[u]*dinv[u]; conv[v] = dinv[v]*(hs[v] + sum_in hs[u]) + b.
// R6: quarter-wave uint2 gather (4 rows in flight/iter, was 2);
// gemm2 fused into conv1 epilogue (wave holds full h1 row -> shfl-gemm w/ W2 in LDS);
// classifier head fused into conv2 (z[v]=h2[v]@Wl, 2 floats -> pool reads 0.8MB not 25.6MB).

#define HDIM 64
#define NB 256     // dst-range buckets (N <= 131072: src fits 17 bits, local dst 9)

static __device__ __forceinline__ unsigned bf16_bits(float f) {  // RNE
    unsigned u = __float_as_uint(f);
    return (u + 0x7fff + ((u >> 16) & 1)) >> 16;
}
static __device__ __forceinline__ float bflo(unsigned w) { return __uint_as_float(w << 16); }
static __device__ __forceinline__ float bfhi(unsigned w) { return __uint_as_float(w & 0xffff0000u); }

__global__ void k_bcount(const int* __restrict__ dst, int* __restrict__ bucket_cnt,
                         int E, int npb, int chunk) {
    __shared__ int lh[NB];
    int tid = threadIdx.x;
    if (tid < NB) lh[tid] = 0;
    __syncthreads();
    int e0 = blockIdx.x * chunk, e1 = min(E, e0 + chunk);
    for (int e = e0 + tid; e < e1; e += 1024)
        atomicAdd(&lh[(unsigned)dst[e] / (unsigned)npb], 1);
    __syncthreads();
    if (tid < NB && lh[tid]) atomicAdd(&bucket_cnt[tid], lh[tid]);
}

__global__ void k_bscan(const int* __restrict__ bucket_cnt, int* __restrict__ bucket_start,
                        int* __restrict__ bucket_cursor) {
    if (threadIdx.x == 0) {
        int s = 0;
        for (int i = 0; i < NB; ++i) { bucket_start[i] = s; bucket_cursor[i] = s; s += bucket_cnt[i]; }
        bucket_start[NB] = s;
    }
}

__global__ __launch_bounds__(1024) void k_bscatter(const int* __restrict__ src,
        const int* __restrict__ dst, int* __restrict__ bucket_cursor,
        unsigned* __restrict__ ebuf, int E, int npb, int chunk) {
    __shared__ int lh[NB], base[NB], lcur[NB];
    int tid = threadIdx.x;
    if (tid < NB) lh[tid] = 0;
    __syncthreads();
    int e0 = blockIdx.x * chunk, e1 = min(E, e0 + chunk);
    for (int e = e0 + tid; e < e1; e += 1024)
        atomicAdd(&lh[(unsigned)dst[e] / (unsigned)npb], 1);
    __syncthreads();
    if (tid < NB) {
        base[tid] = lh[tid] ? atomicAdd(&bucket_cursor[tid], lh[tid]) : 0;
        lcur[tid] = 0;
    }
    __syncthreads();
    for (int e = e0 + tid; e < e1; e += 1024) {
        int d = dst[e];
        unsigned b = (unsigned)d / (unsigned)npb;
        unsigned ld = (unsigned)d - b * (unsigned)npb;
        int off = atomicAdd(&lcur[b], 1);
        ebuf[base[b] + off] = (ld << 17) | (unsigned)src[e];  // contiguous runs
    }
}

// One WG per bucket: LDS histogram -> scan -> row_start/cnt/dinv + csr fill.
__global__ __launch_bounds__(1024) void k_bfill(const unsigned* __restrict__ ebuf,
        const int* __restrict__ bucket_start, int* __restrict__ row_start,
        int* __restrict__ cnt, float* __restrict__ dinv, int* __restrict__ csr,
        int N, int npb) {
    __shared__ int h[512], p[512], c[512];
    int b = blockIdx.x, tid = threadIdx.x;
    int vlo = b * npb;
    int vcnt = min(npb, N - vlo);
    if (vcnt <= 0) return;                    // uniform across block
    for (int i = tid; i < 512; i += 1024) h[i] = 0;
    __syncthreads();
    int e0 = bucket_start[b], e1 = bucket_start[b + 1];
    for (int e = e0 + tid; e < e1; e += 1024)
        atomicAdd(&h[ebuf[e] >> 17], 1);
    __syncthreads();
    if (tid < 512) p[tid] = h[tid];
    __syncthreads();
    for (int off = 1; off < 512; off <<= 1) { // Hillis-Steele inclusive scan
        int v = 0;
        if (tid < 512 && tid >= off) v = p[tid - off];
        __syncthreads();
        if (tid < 512) p[tid] += v;
        __syncthreads();
    }
    if (tid < vcnt) {
        int excl = p[tid] - h[tid];
        int v = vlo + tid;
        row_start[v] = e0 + excl;
        cnt[v] = h[tid];
        dinv[v] = rsqrtf((float)(h[tid] + 1));
        c[tid] = excl;
    }
    __syncthreads();
    for (int e = e0 + tid; e < e1; e += 1024) {
        unsigned ed = ebuf[e];
        int off = atomicAdd(&c[ed >> 17], 1);
        csr[e0 + off] = (int)(ed & 0x1FFFFu);
    }
}

// hsb[v] = bf16x2-packed row of dinv[v] * (X[v] @ W1)   (W1 f32 [128,64])
__global__ void k_gemm1(const float* __restrict__ X, const float* __restrict__ W,
                        const float* __restrict__ dinv, unsigned* __restrict__ hsb, int n) {
    __shared__ float Ws[128 * 64];
    __shared__ float Xs[4][128];
    for (int i = threadIdx.x; i < 128 * 64; i += 256) Ws[i] = W[i];
    __syncthreads();
    int lane = threadIdx.x & 63;
    int wv = threadIdx.x >> 6;
    int v = blockIdx.x * 4 + wv;
    if (v >= n) return;
    const float* xr = X + (size_t)v * 128;
    for (int i = lane; i < 128; i += 64) Xs[wv][i] = xr[i];  // wave-private, no barrier
    float acc = 0.f;
#pragma unroll
    for (int k = 0; k < 128; ++k)
        acc = fmaf(Xs[wv][k], Ws[k * 64 + lane], acc);
    float val = acc * dinv[v];
    float other = __shfl_xor(val, 1, 64);
    if ((lane & 1) == 0)
        hsb[(size_t)v * 32 + (lane >> 1)] = bf16_bits(val) | (bf16_bits(other) << 16);
}

// conv1 + gemm2 fused: gather hs1 (bf16 rows), h1 = relu(dinv*acc + b1),
// hs2 = dinv * (h1 @ W2), packed bf16 out. Quarter-wave gather: 4 rows/iter.
__global__ void k_conv_mid(const unsigned* __restrict__ hsb, const int* __restrict__ row_start,
                           const int* __restrict__ cnt, const int* __restrict__ csr,
                           const float* __restrict__ dinv, const float* __restrict__ bias,
                           const float* __restrict__ W2, unsigned* __restrict__ hsbB, int n) {
    __shared__ float Ws[64 * 64];
    for (int i = threadIdx.x; i < 64 * 64; i += 256) Ws[i] = W2[i];
    __syncthreads();
    int v = (blockIdx.x * 256 + threadIdx.x) >> 6;
    int lane = threadIdx.x & 63;
    if (v >= n) return;                       // no barriers below
    const uint2* hs2p = (const uint2*)hsb;
    int quarter = lane >> 4, q = lane & 15;
    float a0 = 0.f, a1 = 0.f, a2 = 0.f, a3 = 0.f;
    if (quarter == 0) {                       // self-loop term
        uint2 s = hs2p[(size_t)v * 16 + q];
        a0 = bflo(s.x); a1 = bfhi(s.x); a2 = bflo(s.y); a3 = bfhi(s.y);
    }
    int rs = row_start[v], c = cnt[v];
    for (int base = 0; base < c; base += 64) {
        int m = c - base; if (m > 64) m = 64;
        int idx = (lane < m) ? csr[rs + base + lane] : 0;
        for (int j = 0; j < m; j += 4) {
            int u = __shfl(idx, j + quarter, 64);
            if (j + quarter < m) {
                uint2 wn = hs2p[(size_t)u * 16 + q];
                a0 += bflo(wn.x); a1 += bfhi(wn.x); a2 += bflo(wn.y); a3 += bfhi(wn.y);
            }
        }
    }
    a0 += __shfl_xor(a0, 16, 64); a0 += __shfl_xor(a0, 32, 64);
    a1 += __shfl_xor(a1, 16, 64); a1 += __shfl_xor(a1, 32, 64);
    a2 += __shfl_xor(a2, 16, 64); a2 += __shfl_xor(a2, 32, 64);
    a3 += __shfl_xor(a3, 16, 64); a3 += __shfl_xor(a3, 32, 64);
    float dv = dinv[v];
    float4 bb = ((const float4*)bias)[q];
    float r0 = fmaxf(fmaf(dv, a0, bb.x), 0.f);
    float r1 = fmaxf(fmaf(dv, a1, bb.y), 0.f);
    float r2 = fmaxf(fmaf(dv, a2, bb.z), 0.f);
    float r3 = fmaxf(fmaf(dv, a3, bb.w), 0.f);
    // h1 row lives in the wave (lane q holds features 4q..4q+3, all quarters identical)
    float acc = 0.f;
#pragma unroll
    for (int k = 0; k < 64; k += 4) {
        int sl = k >> 2;
        acc = fmaf(__shfl(r0, sl, 64), Ws[(k + 0) * 64 + lane], acc);
        acc = fmaf(__shfl(r1, sl, 64), Ws[(k + 1) * 64 + lane], acc);
        acc = fmaf(__shfl(r2, sl, 64), Ws[(k + 2) * 64 + lane], acc);
        acc = fmaf(__shfl(r3, sl, 64), Ws[(k + 3) * 64 + lane], acc);
    }
    float val = acc * dv;
    float other = __shfl_xor(val, 1, 64);
    if ((lane & 1) == 0)
        hsbB[(size_t)v * 32 + (lane >> 1)] = bf16_bits(val) | (bf16_bits(other) << 16);
}

// conv2 + head fused: gather hs2, h2 = relu(dinv*acc + b2), z[v] = h2 @ Wl (2 floats).
__global__ void k_conv_out(const unsigned* __restrict__ hsb, const int* __restrict__ row_start,
                           const int* __restrict__ cnt, const int* __restrict__ csr,
                           const float* __restrict__ dinv, const float* __restrict__ bias,
                           const float* __restrict__ Wl, float2* __restrict__ z, int n) {
    int v = (blockIdx.x * 256 + threadIdx.x) >> 6;
    int lane = threadIdx.x & 63;
    if (v >= n) return;
    const uint2* hs2p = (const uint2*)hsb;
    int quarter = lane >> 4, q = lane & 15;
    float a0 = 0.f, a1 = 0.f, a2 = 0.f, a3 = 0.f;
    if (quarter == 0) {
        uint2 s = hs2p[(size_t)v * 16 + q];
        a0 = bflo(s.x); a1 = bfhi(s.x); a2 = bflo(s.y); a3 = bfhi(s.y);
    }
    int rs = row_start[v], c = cnt[v];
    for (int base = 0; base < c; base += 64) {
        int m = c - base; if (m > 64) m = 64;
        int idx = (lane < m) ? csr[rs + base + lane] : 0;
        for (int j = 0; j < m; j += 4) {
            int u = __shfl(idx, j + quarter, 64);
            if (j + quarter < m) {
                uint2 wn = hs2p[(size_t)u * 16 + q];
                a0 += bflo(wn.x); a1 += bfhi(wn.x); a2 += bflo(wn.y); a3 += bfhi(wn.y);
            }
        }
    }
    a0 += __shfl_xor(a0, 16, 64); a0 += __shfl_xor(a0, 32, 64);
    a1 += __shfl_xor(a1, 16, 64); a1 += __shfl_xor(a1, 32, 64);
    a2 += __shfl_xor(a2, 16, 64); a2 += __shfl_xor(a2, 32, 64);
    a3 += __shfl_xor(a3, 16, 64); a3 += __shfl_xor(a3, 32, 64);
    float dv = dinv[v];
    float4 bb = ((const float4*)bias)[q];
    float r0 = fmaxf(fmaf(dv, a0, bb.x), 0.f);
    float r1 = fmaxf(fmaf(dv, a1, bb.y), 0.f);
    float r2 = fmaxf(fmaf(dv, a2, bb.z), 0.f);
    float r3 = fmaxf(fmaf(dv, a3, bb.w), 0.f);
    const float4* Wl4 = (const float4*)Wl;    // [64][2] -> pairs of rows
    float4 w01 = Wl4[2 * q];                  // {Wl[4q][0],Wl[4q][1],Wl[4q+1][0],Wl[4q+1][1]}
    float4 w23 = Wl4[2 * q + 1];
    float c0 = r0 * w01.x + r1 * w01.z + r2 * w23.x + r3 * w23.z;
    float c1 = r0 * w01.y + r1 * w01.w + r2 * w23.y + r3 * w23.w;
    c0 += __shfl_xor(c0, 1, 64); c1 += __shfl_xor(c1, 1, 64);
    c0 += __shfl_xor(c0, 2, 64); c1 += __shfl_xor(c1, 2, 64);
    c0 += __shfl_xor(c0, 4, 64); c1 += __shfl_xor(c1, 4, 64);
    c0 += __shfl_xor(c0, 8, 64); c1 += __shfl_xor(c1, 8, 64);
    if (lane == 0) z[v] = make_float2(c0, c1);
}

static __device__ __forceinline__ int lower_bound(const int* __restrict__ a, int n, int key) {
    int lo = 0, hi = n;
    while (lo < hi) {
        int mid = (lo + hi) >> 1;
        if (a[mid] < key) lo = mid + 1; else hi = mid;
    }
    return lo;
}

// One wave per graph: out[g] = mean(z[lo:hi]) + bl  (batch sorted).
__global__ void k_pool_z(const float2* __restrict__ z, const int* __restrict__ batch,
                         const float* __restrict__ bl, float* __restrict__ out, int N, int B) {
    int g = (blockIdx.x * 256 + threadIdx.x) >> 6;
    int lane = threadIdx.x & 63;
    if (g >= B) return;
    int lo = lower_bound(batch, N, g);
    int hi = lower_bound(batch, N, g + 1);
    float c0 = 0.f, c1 = 0.f;
    for (int v = lo + lane; v < hi; v += 64) {
        float2 t = z[v];
        c0 += t.x; c1 += t.y;
    }
    #pragma unroll
    for (int off = 32; off; off >>= 1) {
        c0 += __shfl_xor(c0, off, 64);
        c1 += __shfl_xor(c1, off, 64);
    }
    if (lane == 0) {
        float inv = 1.0f / fmaxf((float)(hi - lo), 1.0f);
        out[g * 2 + 0] = c0 * inv + bl[0];
        out[g * 2 + 1] = c1 * inv + bl[1];
    }
}

extern "C" void kernel_launch(void* const* d_in, const int* in_sizes, int n_in,
                              void* d_out, int out_size, void* d_ws, size_t ws_size,
                              hipStream_t stream) {
    const float* x  = (const float*)d_in[0];   // [N,128] f32
    const int* edge = (const int*)d_in[1];     // [2,E] i32
    const int* batch= (const int*)d_in[2];     // [N] i32 (sorted)
    const float* W1 = (const float*)d_in[3];   // [128,64]
    const float* b1 = (const float*)d_in[4];   // [64]
    const float* W2 = (const float*)d_in[5];   // [64,64]
    const float* b2 = (const float*)d_in[6];   // [64]
    const float* Wl = (const float*)d_in[7];   // [64,2]
    const float* bl = (const float*)d_in[8];   // [2]
    float* out = (float*)d_out;

    const int N = in_sizes[2];
    const int E = in_sizes[1] / 2;
    const int B = out_size / 2;
    const int* srcp = edge;
    const int* dstp = edge + E;
    const int npb = (N + NB - 1) / NB;         // nodes per bucket (391 @ N=100K, <=512)

    // workspace carve-up (256B aligned); ~53 MB
    char* w = (char*)d_ws;
    auto carve = [&](size_t bytes) { void* p = (void*)w; w += (bytes + 255) & ~(size_t)255; return p; };
    int*      cnt    = (int*)carve((size_t)N * 4);
    int*      rsA    = (int*)carve((size_t)N * 4);
    float*    dinv   = (float*)carve((size_t)N * 4);
    int*      bcnt   = (int*)carve((NB + 8) * 4);
    int*      bstart = (int*)carve((NB + 8) * 4);
    int*      bcur   = (int*)carve((NB + 8) * 4);
    int*      csr    = (int*)carve((size_t)E * 4);
    unsigned* ebuf   = (unsigned*)carve((size_t)E * 4);
    unsigned* hsbA   = (unsigned*)carve((size_t)N * 32 * 4);   // bf16x2 hs layer1
    unsigned* hsbB   = (unsigned*)carve((size_t)N * 32 * 4);   // bf16x2 hs layer2
    float2*   zbuf   = (float2*)carve((size_t)N * 8);          // per-node head output

    hipMemsetAsync(bcnt, 0, NB * 4, stream);

    const int SGRID = 256;                      // blocks for count/scatter
    const int chunk = (E + SGRID - 1) / SGRID;  // edges per block
    int wbl = (N + 3) / 4;                      // 4 waves (nodes) per 256-thread block

    k_bcount<<<SGRID, 1024, 0, stream>>>(dstp, bcnt, E, npb, chunk);
    k_bscan<<<1, 64, 0, stream>>>(bcnt, bstart, bcur);
    k_bscatter<<<SGRID, 1024, 0, stream>>>(srcp, dstp, bcur, ebuf, E, npb, chunk);
    k_bfill<<<NB, 1024, 0, stream>>>(ebuf, bstart, rsA, cnt, dinv, csr, N, npb);

    k_gemm1<<<wbl, 256, 0, stream>>>(x, W1, dinv, hsbA, N);
    k_conv_mid<<<wbl, 256, 0, stream>>>(hsbA, rsA, cnt, csr, dinv, b1, W2, hsbB, N);
    k_conv_out<<<wbl, 256, 0, stream>>>(hsbB, rsA, cnt, csr, dinv, b2, Wl, zbuf, N);

    k_pool_z<<<(B * 64 + 255) / 256, 256, 0, stream>>>(zbuf, batch, bl, out, N, B);
}

// Round 7
// 403.731 us; speedup vs baseline: 3.5028x; 1.2247x over previous
//
#include <hip/hip_runtime.h>
#include <hip/hip_bf16.h>

// GCN: h1 = relu(Dinv (A+I) Dinv (x W1) + b1); h2 = relu(same with W2);
// out = mean-pool-by-graph(h2) @ Wl + bl.
// Identity: hs[u] = (xW)[u]*dinv[u]; conv[v] = dinv[v]*(hs[v] + sum_in hs[u]) + b.
// R7: eighth-wave uint4 gather (8 rows/iter in flight; R6's quarter-wave was
// latency-bound at 4); epilogue shfls -> readlane (scalar, not ds_bpermute);
// sort pipe: bcount saves per-block histograms, bscan2 scans them -> bscatter
// needs no re-histogram / global cursors; gemm1: X in regs, 1 LDS read per FMA.

#define HDIM 64
#define NB 256      // dst-range buckets (N <= 131072: src fits 17 bits, local dst 9)
#define SGRID 256   // blocks for bcount/bscatter

static __device__ __forceinline__ unsigned bf16_bits(float f) {  // RNE
    unsigned u = __float_as_uint(f);
    return (u + 0x7fff + ((u >> 16) & 1)) >> 16;
}
static __device__ __forceinline__ float bflo(unsigned w) { return __uint_as_float(w << 16); }
static __device__ __forceinline__ float bfhi(unsigned w) { return __uint_as_float(w & 0xffff0000u); }
static __device__ __forceinline__ float rdlane(float v, int l) {
    return __uint_as_float(__builtin_amdgcn_readlane(__float_as_uint(v), l));
}

__global__ __launch_bounds__(1024) void k_bcount(const int* __restrict__ dst,
        int* __restrict__ blkhist, int E, int npb, int chunk) {
    __shared__ int lh[NB];
    int tid = threadIdx.x;
    if (tid < NB) lh[tid] = 0;
    __syncthreads();
    int e0 = blockIdx.x * chunk, e1 = min(E, e0 + chunk);
    for (int e = e0 + tid; e < e1; e += 1024)
        atomicAdd(&lh[(unsigned)dst[e] / (unsigned)npb], 1);
    __syncthreads();
    if (tid < NB) blkhist[blockIdx.x * NB + tid] = lh[tid];
}

// One block per bucket b: exclusive scan of blkhist[*][b] over blocks (in place),
// total -> bcnt[b].
__global__ void k_bscan2(int* __restrict__ blkhist, int* __restrict__ bcnt) {
    __shared__ int s[SGRID];
    int b = blockIdx.x, t = threadIdx.x;
    int orig = blkhist[t * NB + b];
    s[t] = orig;
    __syncthreads();
    for (int off = 1; off < SGRID; off <<= 1) {
        int v = 0;
        if (t >= off) v = s[t - off];
        __syncthreads();
        s[t] += v;
        __syncthreads();
    }
    blkhist[t * NB + b] = s[t] - orig;        // exclusive prefix
    if (t == SGRID - 1) bcnt[b] = s[t];
}

__global__ void k_bscan(const int* __restrict__ bcnt, int* __restrict__ bstart) {
    if (threadIdx.x == 0) {
        int s = 0;
        for (int i = 0; i < NB; ++i) { bstart[i] = s; s += bcnt[i]; }
        bstart[NB] = s;
    }
}

__global__ __launch_bounds__(1024) void k_bscatter(const int* __restrict__ src,
        const int* __restrict__ dst, const int* __restrict__ bstart,
        const int* __restrict__ blkhist, unsigned* __restrict__ ebuf,
        int E, int npb, int chunk) {
    __shared__ int base[NB], lcur[NB];
    int tid = threadIdx.x;
    if (tid < NB) {
        base[tid] = bstart[tid] + blkhist[blockIdx.x * NB + tid];
        lcur[tid] = 0;
    }
    __syncthreads();
    int e0 = blockIdx.x * chunk, e1 = min(E, e0 + chunk);
    for (int e = e0 + tid; e < e1; e += 1024) {
        int d = dst[e];
        unsigned b = (unsigned)d / (unsigned)npb;
        unsigned ld = (unsigned)d - b * (unsigned)npb;
        int off = atomicAdd(&lcur[b], 1);
        ebuf[base[b] + off] = (ld << 17) | (unsigned)src[e];  // contiguous runs
    }
}

// One WG per bucket: LDS histogram -> scan -> row_start/cnt/dinv + csr fill.
__global__ __launch_bounds__(1024) void k_bfill(const unsigned* __restrict__ ebuf,
        const int* __restrict__ bucket_start, int* __restrict__ row_start,
        int* __restrict__ cnt, float* __restrict__ dinv, int* __restrict__ csr,
        int N, int npb) {
    __shared__ int h[512], p[512], c[512];
    int b = blockIdx.x, tid = threadIdx.x;
    int vlo = b * npb;
    int vcnt = min(npb, N - vlo);
    if (vcnt <= 0) return;                    // uniform across block
    for (int i = tid; i < 512; i += 1024) h[i] = 0;
    __syncthreads();
    int e0 = bucket_start[b], e1 = bucket_start[b + 1];
    for (int e = e0 + tid; e < e1; e += 1024)
        atomicAdd(&h[ebuf[e] >> 17], 1);
    __syncthreads();
    if (tid < 512) p[tid] = h[tid];
    __syncthreads();
    for (int off = 1; off < 512; off <<= 1) { // Hillis-Steele inclusive scan
        int v = 0;
        if (tid < 512 && tid >= off) v = p[tid - off];
        __syncthreads();
        if (tid < 512) p[tid] += v;
        __syncthreads();
    }
    if (tid < vcnt) {
        int excl = p[tid] - h[tid];
        int v = vlo + tid;
        row_start[v] = e0 + excl;
        cnt[v] = h[tid];
        dinv[v] = rsqrtf((float)(h[tid] + 1));
        c[tid] = excl;
    }
    __syncthreads();
    for (int e = e0 + tid; e < e1; e += 1024) {
        unsigned ed = ebuf[e];
        int off = atomicAdd(&c[ed >> 17], 1);
        csr[e0 + off] = (int)(ed & 0x1FFFFu);
    }
}

// hsb[v] = bf16x2-packed row of dinv[v] * (X[v] @ W1). X row in 2 VGPRs,
// inner loop = readlane + 1 LDS read + FMA. 8 nodes per wave.
#define GNPW 8
__global__ void k_gemm1(const float* __restrict__ X, const float* __restrict__ W,
                        const float* __restrict__ dinv, unsigned* __restrict__ hsb, int n) {
    __shared__ float Ws[128 * 64];
    for (int i = threadIdx.x; i < 128 * 64; i += 256) Ws[i] = W[i];
    __syncthreads();
    int lane = threadIdx.x & 63;
    int wv = threadIdx.x >> 6;
    int v0 = (blockIdx.x * 4 + wv) * GNPW;
    for (int nn = 0; nn < GNPW; ++nn) {
        int v = v0 + nn;
        if (v >= n) return;                   // wave-uniform
        const float* xr = X + (size_t)v * 128;
        float r0 = xr[lane], r1 = xr[64 + lane];
        float a0 = 0.f, a1 = 0.f, a2 = 0.f, a3 = 0.f;
#pragma unroll
        for (int k = 0; k < 64; k += 4) {
            a0 = fmaf(rdlane(r0, k + 0), Ws[(k + 0) * 64 + lane], a0);
            a1 = fmaf(rdlane(r0, k + 1), Ws[(k + 1) * 64 + lane], a1);
            a2 = fmaf(rdlane(r0, k + 2), Ws[(k + 2) * 64 + lane], a2);
            a3 = fmaf(rdlane(r0, k + 3), Ws[(k + 3) * 64 + lane], a3);
        }
#pragma unroll
        for (int k = 0; k < 64; k += 4) {
            a0 = fmaf(rdlane(r1, k + 0), Ws[(64 + k + 0) * 64 + lane], a0);
            a1 = fmaf(rdlane(r1, k + 1), Ws[(64 + k + 1) * 64 + lane], a1);
            a2 = fmaf(rdlane(r1, k + 2), Ws[(64 + k + 2) * 64 + lane], a2);
            a3 = fmaf(rdlane(r1, k + 3), Ws[(64 + k + 3) * 64 + lane], a3);
        }
        float val = ((a0 + a1) + (a2 + a3)) * dinv[v];
        float other = __shfl_xor(val, 1, 64);
        if ((lane & 1) == 0)
            hsb[(size_t)v * 32 + (lane >> 1)] = bf16_bits(val) | (bf16_bits(other) << 16);
    }
}

// Eighth-wave gather core: lane = oct*8+o; o covers features 8o..8o+7 (uint4),
// octs cover 8 neighbor rows per iteration. Returns relu'd h row (r[0..7] per o).
#define GATHER_BODY                                                            \
    const uint4* hs4p = (const uint4*)hsb;                                     \
    int o = lane & 7, oct = lane >> 3;                                         \
    float a0=0.f,a1=0.f,a2=0.f,a3=0.f,a4=0.f,a5=0.f,a6=0.f,a7=0.f;             \
    if (oct == 0) {                                                            \
        uint4 s = hs4p[(size_t)v * 8 + o];                                     \
        a0=bflo(s.x);a1=bfhi(s.x);a2=bflo(s.y);a3=bfhi(s.y);                   \
        a4=bflo(s.z);a5=bfhi(s.z);a6=bflo(s.w);a7=bfhi(s.w);                   \
    }                                                                          \
    int rs = row_start[v], c = cnt[v];                                         \
    for (int base = 0; base < c; base += 64) {                                 \
        int m = c - base; if (m > 64) m = 64;                                  \
        int idx = (lane < m) ? csr[rs + base + lane] : 0;                      \
        for (int j = 0; j < m; j += 8) {                                       \
            int u = __shfl(idx, j + oct, 64);                                  \
            if (j + oct < m) {                                                 \
                uint4 wn = hs4p[(size_t)u * 8 + o];                            \
                a0+=bflo(wn.x);a1+=bfhi(wn.x);a2+=bflo(wn.y);a3+=bfhi(wn.y);   \
                a4+=bflo(wn.z);a5+=bfhi(wn.z);a6+=bflo(wn.w);a7+=bfhi(wn.w);   \
            }                                                                  \
        }                                                                      \
    }                                                                          \
    a0+=__shfl_xor(a0,8,64);a0+=__shfl_xor(a0,16,64);a0+=__shfl_xor(a0,32,64); \
    a1+=__shfl_xor(a1,8,64);a1+=__shfl_xor(a1,16,64);a1+=__shfl_xor(a1,32,64); \
    a2+=__shfl_xor(a2,8,64);a2+=__shfl_xor(a2,16,64);a2+=__shfl_xor(a2,32,64); \
    a3+=__shfl_xor(a3,8,64);a3+=__shfl_xor(a3,16,64);a3+=__shfl_xor(a3,32,64); \
    a4+=__shfl_xor(a4,8,64);a4+=__shfl_xor(a4,16,64);a4+=__shfl_xor(a4,32,64); \
    a5+=__shfl_xor(a5,8,64);a5+=__shfl_xor(a5,16,64);a5+=__shfl_xor(a5,32,64); \
    a6+=__shfl_xor(a6,8,64);a6+=__shfl_xor(a6,16,64);a6+=__shfl_xor(a6,32,64); \
    a7+=__shfl_xor(a7,8,64);a7+=__shfl_xor(a7,16,64);a7+=__shfl_xor(a7,32,64); \
    float dv = dinv[v];                                                        \
    float4 bb0 = ((const float4*)bias)[2 * o];                                 \
    float4 bb1 = ((const float4*)bias)[2 * o + 1];                             \
    float r0 = fmaxf(fmaf(dv, a0, bb0.x), 0.f);                                \
    float r1 = fmaxf(fmaf(dv, a1, bb0.y), 0.f);                                \
    float r2 = fmaxf(fmaf(dv, a2, bb0.z), 0.f);                                \
    float r3 = fmaxf(fmaf(dv, a3, bb0.w), 0.f);                                \
    float r4 = fmaxf(fmaf(dv, a4, bb1.x), 0.f);                                \
    float r5 = fmaxf(fmaf(dv, a5, bb1.y), 0.f);                                \
    float r6 = fmaxf(fmaf(dv, a6, bb1.z), 0.f);                                \
    float r7 = fmaxf(fmaf(dv, a7, bb1.w), 0.f);

// conv1 + gemm2 fused: h1[k=8j+i] lives in lane j, reg r_i (replicated over octs).
__global__ void k_conv_mid(const unsigned* __restrict__ hsb, const int* __restrict__ row_start,
                           const int* __restrict__ cnt, const int* __restrict__ csr,
                           const float* __restrict__ dinv, const float* __restrict__ bias,
                           const float* __restrict__ W2, unsigned* __restrict__ hsbB, int n) {
    __shared__ float Ws[64 * 64];
    for (int i = threadIdx.x; i < 64 * 64; i += 256) Ws[i] = W2[i];
    __syncthreads();
    int v = (blockIdx.x * 256 + threadIdx.x) >> 6;
    int lane = threadIdx.x & 63;
    if (v >= n) return;                       // no barriers below
    GATHER_BODY
    float acc = 0.f;
#pragma unroll
    for (int j = 0; j < 8; ++j) {
        acc = fmaf(rdlane(r0, j), Ws[(8 * j + 0) * 64 + lane], acc);
        acc = fmaf(rdlane(r1, j), Ws[(8 * j + 1) * 64 + lane], acc);
        acc = fmaf(rdlane(r2, j), Ws[(8 * j + 2) * 64 + lane], acc);
        acc = fmaf(rdlane(r3, j), Ws[(8 * j + 3) * 64 + lane], acc);
        acc = fmaf(rdlane(r4, j), Ws[(8 * j + 4) * 64 + lane], acc);
        acc = fmaf(rdlane(r5, j), Ws[(8 * j + 5) * 64 + lane], acc);
        acc = fmaf(rdlane(r6, j), Ws[(8 * j + 6) * 64 + lane], acc);
        acc = fmaf(rdlane(r7, j), Ws[(8 * j + 7) * 64 + lane], acc);
    }
    float val = acc * dv;
    float other = __shfl_xor(val, 1, 64);
    if ((lane & 1) == 0)
        hsbB[(size_t)v * 32 + (lane >> 1)] = bf16_bits(val) | (bf16_bits(other) << 16);
}

// conv2 + head fused: z[v] = h2[v] @ Wl (2 floats per node).
__global__ void k_conv_out(const unsigned* __restrict__ hsb, const int* __restrict__ row_start,
                           const int* __restrict__ cnt, const int* __restrict__ csr,
                           const float* __restrict__ dinv, const float* __restrict__ bias,
                           const float* __restrict__ Wl, float2* __restrict__ z, int n) {
    int v = (blockIdx.x * 256 + threadIdx.x) >> 6;
    int lane = threadIdx.x & 63;
    if (v >= n) return;
    GATHER_BODY
    const float4* Wl4 = (const float4*)Wl;    // [64][2] -> 2 rows per float4
    float4 wA = Wl4[4 * o + 0];               // rows 8o,8o+1
    float4 wB = Wl4[4 * o + 1];               // rows 8o+2,8o+3
    float4 wC = Wl4[4 * o + 2];
    float4 wD = Wl4[4 * o + 3];
    float c0 = r0*wA.x + r1*wA.z + r2*wB.x + r3*wB.z + r4*wC.x + r5*wC.z + r6*wD.x + r7*wD.z;
    float c1 = r0*wA.y + r1*wA.w + r2*wB.y + r3*wB.w + r4*wC.y + r5*wC.w + r6*wD.y + r7*wD.w;
    c0 += __shfl_xor(c0, 1, 64); c1 += __shfl_xor(c1, 1, 64);
    c0 += __shfl_xor(c0, 2, 64); c1 += __shfl_xor(c1, 2, 64);
    c0 += __shfl_xor(c0, 4, 64); c1 += __shfl_xor(c1, 4, 64);
    if (lane == 0) z[v] = make_float2(c0, c1);
}

static __device__ __forceinline__ int lower_bound(const int* __restrict__ a, int n, int key) {
    int lo = 0, hi = n;
    while (lo < hi) {
        int mid = (lo + hi) >> 1;
        if (a[mid] < key) lo = mid + 1; else hi = mid;
    }
    return lo;
}

// One wave per graph: out[g] = mean(z[lo:hi]) + bl  (batch sorted).
__global__ void k_pool_z(const float2* __restrict__ z, const int* __restrict__ batch,
                         const float* __restrict__ bl, float* __restrict__ out, int N, int B) {
    int g = (blockIdx.x * 256 + threadIdx.x) >> 6;
    int lane = threadIdx.x & 63;
    if (g >= B) return;
    int lo = lower_bound(batch, N, g);
    int hi = lower_bound(batch, N, g + 1);
    float c0 = 0.f, c1 = 0.f;
    for (int v = lo + lane; v < hi; v += 64) {
        float2 t = z[v];
        c0 += t.x; c1 += t.y;
    }
    #pragma unroll
    for (int off = 32; off; off >>= 1) {
        c0 += __shfl_xor(c0, off, 64);
        c1 += __shfl_xor(c1, off, 64);
    }
    if (lane == 0) {
        float inv = 1.0f / fmaxf((float)(hi - lo), 1.0f);
        out[g * 2 + 0] = c0 * inv + bl[0];
        out[g * 2 + 1] = c1 * inv + bl[1];
    }
}

extern "C" void kernel_launch(void* const* d_in, const int* in_sizes, int n_in,
                              void* d_out, int out_size, void* d_ws, size_t ws_size,
                              hipStream_t stream) {
    const float* x  = (const float*)d_in[0];   // [N,128] f32
    const int* edge = (const int*)d_in[1];     // [2,E] i32
    const int* batch= (const int*)d_in[2];     // [N] i32 (sorted)
    const float* W1 = (const float*)d_in[3];   // [128,64]
    const float* b1 = (const float*)d_in[4];   // [64]
    const float* W2 = (const float*)d_in[5];   // [64,64]
    const float* b2 = (const float*)d_in[6];   // [64]
    const float* Wl = (const float*)d_in[7];   // [64,2]
    const float* bl = (const float*)d_in[8];   // [2]
    float* out = (float*)d_out;

    const int N = in_sizes[2];
    const int E = in_sizes[1] / 2;
    const int B = out_size / 2;
    const int* srcp = edge;
    const int* dstp = edge + E;
    const int npb = (N + NB - 1) / NB;         // nodes per bucket (391 @ N=100K, <=512)

    // workspace carve-up (256B aligned); ~54 MB
    char* w = (char*)d_ws;
    auto carve = [&](size_t bytes) { void* p = (void*)w; w += (bytes + 255) & ~(size_t)255; return p; };
    int*      cnt     = (int*)carve((size_t)N * 4);
    int*      rsA     = (int*)carve((size_t)N * 4);
    float*    dinv    = (float*)carve((size_t)N * 4);
    int*      bcnt    = (int*)carve((NB + 8) * 4);
    int*      bstart  = (int*)carve((NB + 8) * 4);
    int*      blkhist = (int*)carve((size_t)SGRID * NB * 4);
    int*      csr     = (int*)carve((size_t)E * 4);
    unsigned* ebuf    = (unsigned*)carve((size_t)E * 4);
    unsigned* hsbA    = (unsigned*)carve((size_t)N * 32 * 4);  // bf16x2 hs layer1
    unsigned* hsbB    = (unsigned*)carve((size_t)N * 32 * 4);  // bf16x2 hs layer2
    float2*   zbuf    = (float2*)carve((size_t)N * 8);         // per-node head output

    const int chunk = (E + SGRID - 1) / SGRID;  // edges per block
    int wbl = (N + 3) / 4;                      // 4 waves (nodes) per 256-thread block

    k_bcount<<<SGRID, 1024, 0, stream>>>(dstp, blkhist, E, npb, chunk);
    k_bscan2<<<NB, SGRID, 0, stream>>>(blkhist, bcnt);
    k_bscan<<<1, 64, 0, stream>>>(bcnt, bstart);
    k_bscatter<<<SGRID, 1024, 0, stream>>>(srcp, dstp, bstart, blkhist, ebuf, E, npb, chunk);
    k_bfill<<<NB, 1024, 0, stream>>>(ebuf, bstart, rsA, cnt, dinv, csr, N, npb);

    k_gemm1<<<(N + 4 * GNPW - 1) / (4 * GNPW), 256, 0, stream>>>(x, W1, dinv, hsbA, N);
    k_conv_mid<<<wbl, 256, 0, stream>>>(hsbA, rsA, cnt, csr, dinv, b1, W2, hsbB, N);
    k_conv_out<<<wbl, 256, 0, stream>>>(hsbB, rsA, cnt, csr, dinv, b2, Wl, zbuf, N);

    k_pool_z<<<(B * 64 + 255) / 256, 256, 0, stream>>>(zbuf, batch, bl, out, N, B);
}